// Round 9
// baseline (91.992 us; speedup 1.0000x reference)
//
#include <hip/hip_runtime.h>

#define NN  10000
#define NE  640000
#define IC  512
#define H   7
#define HP  8                      // padded g row stride (2x float4)
#define NCH 256                    // K0 bucket chunks
#define CE  (NE / NCH)             // 2500 edges per chunk
#define RG  250                    // row ranges (buckets)
#define RN  40                     // nodes per range
#define CAP 3072                   // bucket capacity (mean 2560, max~2740)

__device__ __forceinline__ float wave_sum(float v) {
    #pragma unroll
    for (int off = 32; off; off >>= 1) v += __shfl_xor(v, off);
    return v;
}

// K0: bucket edges by row-range. LDS counting sort of the 2500-edge chunk,
// one global cursor atomic per (block,range) to reserve, coalesced group
// write-out of packed {col | rowlocal<<14, ew}.
__global__ __launch_bounds__(1024) void k_bucket(
    const int* __restrict__ row, const int* __restrict__ col,
    const float* __restrict__ ew, int* __restrict__ gcur,
    int2* __restrict__ gbuf)
{
    __shared__ int   lhist[RG];
    __shared__ int   loffs[RG];
    __shared__ int   lbase[RG];
    __shared__ int   lcur[RG];
    __shared__ int2  st[CE];            // 20 KB staged sorted edges
    __shared__ unsigned short strg[CE]; // 5 KB range per staged slot
    const int tid = threadIdx.x;
    const int base = blockIdx.x * CE;
    if (tid < RG) lhist[tid] = 0;
    __syncthreads();
    int er[3]; float ef[3]; int erg[3];
    #pragma unroll
    for (int k = 0; k < 3; ++k) {
        const int i = tid + k * 1024;
        er[k] = -1;
        if (i < CE) {
            const int e = base + i;
            const int r = row[e], c = col[e];
            const int rg = r / RN, rl = r - rg * RN;
            er[k] = c | (rl << 14);
            ef[k] = ew[e];
            erg[k] = rg;
            atomicAdd(&lhist[rg], 1);
        }
    }
    __syncthreads();
    if (tid < RG) lbase[tid] = tid * CAP + atomicAdd(&gcur[tid], lhist[tid]);
    if (tid < 64) {                      // exclusive scan of lhist (wave 0)
        const int ln = tid;
        int t4[4]; int s4 = 0;
        #pragma unroll
        for (int k = 0; k < 4; ++k) {
            const int j = ln * 4 + k;
            t4[k] = (j < RG) ? lhist[j] : 0;
            s4 += t4[k];
        }
        int s = s4;
        #pragma unroll
        for (int off = 1; off < 64; off <<= 1) {
            const int t = __shfl_up(s, off);
            if (ln >= off) s += t;
        }
        int run = s - s4;
        #pragma unroll
        for (int k = 0; k < 4; ++k) {
            const int j = ln * 4 + k;
            if (j < RG) { loffs[j] = run; lcur[j] = run; }
            run += t4[k];
        }
    }
    __syncthreads();
    #pragma unroll
    for (int k = 0; k < 3; ++k) {
        if (er[k] >= 0) {
            const int pos = atomicAdd(&lcur[erg[k]], 1);
            st[pos] = make_int2(er[k], __float_as_int(ef[k]));
            strg[pos] = (unsigned short)erg[k];
        }
    }
    __syncthreads();
    #pragma unroll
    for (int k = 0; k < 3; ++k) {
        const int i = tid + k * 1024;
        if (i < CE) {
            const int rg = strg[i];
            gbuf[lbase[rg] + (i - loffs[rg])] = st[i];
        }
    }
}

// K1: per-range block: deg from own bucket -> dinv; mm1 (40 rows of x @ W1);
// emits g1 = dinv * h1 only (self term later uses dinv*g1).
__global__ __launch_bounds__(512) void k_deg_mm1(
    const int* __restrict__ gcur, const int2* __restrict__ gbuf,
    const float* __restrict__ x, const float* __restrict__ W1,
    float* __restrict__ dinv, float* __restrict__ g1)
{
    __shared__ float wls[IC * H];       // 14 KB
    __shared__ float ldeg[RN];
    __shared__ float ldv[RN];
    __shared__ float htile[RN][HP];
    const int tid = threadIdx.x, b = blockIdx.x;
    const int wv = tid >> 6, ln = tid & 63;
    if (tid < RN) { ldeg[tid] = 0.0f; htile[tid][7] = 0.0f; }
    for (int i = tid; i < IC * H; i += 512) wls[i] = W1[i];
    __syncthreads();
    const int cnt = gcur[b];
    const int2* bk = gbuf + (size_t)b * CAP;
    for (int i = tid; i < cnt; i += 512) {
        const int2 e = bk[i];
        atomicAdd(&ldeg[e.x >> 14], __int_as_float(e.y));
    }
    __syncthreads();
    if (tid < RN) {
        const float d = rsqrtf(1.0f + ldeg[tid]);
        ldv[tid] = d;
        dinv[b * RN + tid] = d;
    }
    // mm1: wave wv handles local rows wv*5 .. wv*5+4
    for (int q = 0; q < 5; ++q) {
        const int rl = wv * 5 + q;
        const float4* xr4 = (const float4*)(x + (size_t)(b * RN + rl) * IC);
        const float4 a0 = xr4[ln * 2], a1 = xr4[ln * 2 + 1];
        const float e8[8] = {a0.x, a0.y, a0.z, a0.w, a1.x, a1.y, a1.z, a1.w};
        const float* wb = &wls[ln * 8 * H];
        float acc[H] = {};
        #pragma unroll
        for (int m = 0; m < 8; ++m)
            #pragma unroll
            for (int c = 0; c < H; ++c) acc[c] += e8[m] * wb[m * H + c];
        #pragma unroll
        for (int c = 0; c < H; ++c) {
            const float v = wave_sum(acc[c]);
            if (ln == 0) htile[rl][c] = v;
        }
    }
    __syncthreads();
    if (tid < RN * HP) {
        const int n = tid >> 3, j = tid & 7;
        g1[(size_t)(b * RN) * HP + tid] = ldv[n] * htile[n][j];
    }
}

// K2: gather layer 1 + bias + mm2, emits g2 = dinv * (out1 @ W2).
// out1[n] = dinv[n]*(sum_e ew*g1[col] + g1[n]) + b1.
__global__ __launch_bounds__(512) void k_gather1(
    const int* __restrict__ gcur, const int2* __restrict__ gbuf,
    const float* __restrict__ dinv, const float* __restrict__ g1,
    const float* __restrict__ b1, const float* __restrict__ W2,
    float* __restrict__ g2)
{
    __shared__ float acc[RN][9];        // stride 9 (coprime banks)
    __shared__ float vv[RN][HP];
    __shared__ float ldv[RN];
    __shared__ float w2[H * H];
    __shared__ float bb[H];
    const int tid = threadIdx.x, b = blockIdx.x;
    if (tid < RN * 9) ((float*)acc)[tid] = 0.0f;
    if (tid >= 384 && tid < 384 + H * H) w2[tid - 384] = W2[tid - 384];
    if (tid >= 448 && tid < 448 + H) bb[tid - 448] = b1[tid - 448];
    if (tid >= 456 && tid < 456 + RN) ldv[tid - 456] = dinv[b * RN + tid - 456];
    __syncthreads();
    const int cnt = gcur[b];
    const int2* bk = gbuf + (size_t)b * CAP;
    for (int i = tid; i < cnt; i += 512) {
        const int2 e = bk[i];
        const int c = e.x & 16383, rl = e.x >> 14;
        const float w = __int_as_float(e.y);
        const float4* gc = (const float4*)(g1 + (size_t)c * HP);
        const float4 lo = gc[0], hi = gc[1];
        atomicAdd(&acc[rl][0], w * lo.x);
        atomicAdd(&acc[rl][1], w * lo.y);
        atomicAdd(&acc[rl][2], w * lo.z);
        atomicAdd(&acc[rl][3], w * lo.w);
        atomicAdd(&acc[rl][4], w * hi.x);
        atomicAdd(&acc[rl][5], w * hi.y);
        atomicAdd(&acc[rl][6], w * hi.z);
    }
    __syncthreads();
    if (tid < RN * H) {
        const int n = tid / H, k = tid - n * H;
        const int gn = b * RN + n;
        const float di = ldv[n];
        vv[n][k] = di * (acc[n][k] + g1[(size_t)gn * HP + k]) + bb[k];
    }
    __syncthreads();
    if (tid < RN * H) {
        const int n = tid / H, k = tid - n * H;
        const int gn = b * RN + n;
        float o = 0.0f;
        #pragma unroll
        for (int j = 0; j < H; ++j) o += vv[n][j] * w2[j * H + k];
        g2[(size_t)gn * HP + k] = ldv[n] * o;
    }
    if (tid >= 448 && tid < 448 + RN)
        g2[(size_t)(b * RN + tid - 448) * HP + 7] = 0.0f;
}

// K3: gather layer 2 + bias -> final output (stride 7) + reg element.
__global__ __launch_bounds__(512) void k_gather2(
    const int* __restrict__ gcur, const int2* __restrict__ gbuf,
    const float* __restrict__ dinv, const float* __restrict__ g2,
    const float* __restrict__ b2, float* __restrict__ dout)
{
    __shared__ float acc[RN][9];
    __shared__ float ldv[RN];
    __shared__ float bb[H];
    const int tid = threadIdx.x, b = blockIdx.x;
    if (b == 0 && tid == 511) dout[(size_t)NN * H] = 0.0f;   // reg
    if (tid < RN * 9) ((float*)acc)[tid] = 0.0f;
    if (tid >= 448 && tid < 448 + H) bb[tid - 448] = b2[tid - 448];
    if (tid >= 456 && tid < 456 + RN) ldv[tid - 456] = dinv[b * RN + tid - 456];
    __syncthreads();
    const int cnt = gcur[b];
    const int2* bk = gbuf + (size_t)b * CAP;
    for (int i = tid; i < cnt; i += 512) {
        const int2 e = bk[i];
        const int c = e.x & 16383, rl = e.x >> 14;
        const float w = __int_as_float(e.y);
        const float4* gc = (const float4*)(g2 + (size_t)c * HP);
        const float4 lo = gc[0], hi = gc[1];
        atomicAdd(&acc[rl][0], w * lo.x);
        atomicAdd(&acc[rl][1], w * lo.y);
        atomicAdd(&acc[rl][2], w * lo.z);
        atomicAdd(&acc[rl][3], w * lo.w);
        atomicAdd(&acc[rl][4], w * hi.x);
        atomicAdd(&acc[rl][5], w * hi.y);
        atomicAdd(&acc[rl][6], w * hi.z);
    }
    __syncthreads();
    if (tid < RN * H) {
        const int n = tid / H, k = tid - n * H;
        const int gn = b * RN + n;
        const float di = ldv[n];
        dout[(size_t)gn * H + k] = di * (acc[n][k] + g2[(size_t)gn * HP + k]) + bb[k];
    }
}

extern "C" void kernel_launch(void* const* d_in, const int* in_sizes, int n_in,
                              void* d_out, int out_size, void* d_ws, size_t ws_size,
                              hipStream_t stream) {
    const float* x  = (const float*)d_in[0];
    const int*   ei = (const int*)d_in[1];
    const float* ea = (const float*)d_in[2];
    const float* W1 = (const float*)d_in[4];
    const float* b1 = (const float*)d_in[5];
    const float* W2 = (const float*)d_in[6];
    const float* b2 = (const float*)d_in[7];
    float* out = (float*)d_out;

    char* p = (char*)d_ws;
    int* gcur = (int*)p;          p += 1024;
    int2* gbuf = (int2*)p;        p += sizeof(int2) * RG * CAP;    // 6.1 MB
    float* g1 = (float*)p;        p += sizeof(float) * NN * HP;
    float* g2 = (float*)p;        p += sizeof(float) * NN * HP;
    float* dinv = (float*)p;      p += sizeof(float) * NN;

    const int* row = ei;
    const int* col = ei + NE;

    hipMemsetAsync(gcur, 0, RG * sizeof(int), stream);
    k_bucket<<<NCH, 1024, 0, stream>>>(row, col, ea, gcur, gbuf);
    k_deg_mm1<<<RG, 512, 0, stream>>>(gcur, gbuf, x, W1, dinv, g1);
    k_gather1<<<RG, 512, 0, stream>>>(gcur, gbuf, dinv, g1, b1, W2, g2);
    k_gather2<<<RG, 512, 0, stream>>>(gcur, gbuf, dinv, g2, b2, out);
}